// Round 1
// baseline (847.142 us; speedup 1.0000x reference)
//
#include <hip/hip_runtime.h>
#include <hip/hip_bf16.h>
#include <math.h>

// Sizes: N=4096, T=4, F=256, H=8, C=16, P=1024, D=32
#define NN 4096
#define NTROWS 16384   // N*T

typedef __attribute__((ext_vector_type(8))) __bf16 bf16x8;
typedef __attribute__((ext_vector_type(4))) float f32x4;

// ---------------- workspace layout (bytes) ----------------
static constexpr size_t OFF_SCAL   = 0;         // float[16]: 0=l1 1=l2 2=recon_err
static constexpr size_t OFF_CNT    = 64;        // int[4]
static constexpr size_t OFF_BASE   = 80;        // int[4]
static constexpr size_t OFF_PERM   = 256;       // int[4096]
static constexpr size_t OFF_FEAT32 = 16896;     // N*F f32      (4 MB)
static constexpr size_t OFF_FEATB  = 4211200;   // N*F bf16     (2 MB)
static constexpr size_t OFF_FEATPK = 6308352;   // N*F bf16 packed (2 MB)
static constexpr size_t OFF_PACKS  = 8405504;   // 37 * 65536 bf16 (4.85 MB)
static constexpr size_t OFF_R      = 13255168;  // NT*F f32     (16 MB)
static constexpr size_t OFF_EF32   = 30032384;  // NT*F f32     (16 MB)
static constexpr size_t OFF_EFB    = 46809600;  // NT*F bf16    (8 MB)
static constexpr size_t OFF_NPROJ  = 55198208;  // N*F f32      (4 MB)
static constexpr size_t OFF_EPROJ  = 59392512;  // NT*F f32     (16 MB)

__device__ __forceinline__ f32x4 mm_bf16(bf16x8 a, bf16x8 b, f32x4 c){
  return __builtin_amdgcn_mfma_f32_16x16x32_bf16(a, b, c, 0, 0, 0);
}

// ---------------- K1b: pack all B matrices (theta + 16 recon + 4 node + 16 edge) ----
// Pack layout per matrix (65536 bf16): unit u=(ks*16+cf)*64+lane, element i:
//   packed[u*8+i] = mat[cf*16 + (lane&15)][ks*32 + (lane>>4)*8 + i]
// so a b-fragment load is one coalesced 16B/lane read.
__global__ __launch_bounds__(256) void k1b_pack(
    const float* __restrict__ theta, const float* __restrict__ recp,
    const float* __restrict__ nodp,  const float* __restrict__ edgp,
    __bf16* __restrict__ packs)
{
  int b = blockIdx.x;
  const float* src;
  if (b == 0)       src = theta;
  else if (b < 17)  src = recp + (size_t)(b-1)*65536;
  else if (b < 21)  src = nodp + (size_t)(b-17)*65536;
  else              src = edgp + (size_t)(b-21)*65536;
  __bf16* dst = packs + (size_t)b*65536;
  for (int it = 0; it < 32; ++it){
    int u = it*256 + threadIdx.x;
    int lane = u & 63, cf = (u>>6)&15, ks = u>>10;
    int lo = lane & 15, hi = lane >> 4;
    const float* sp = src + (size_t)(cf*16+lo)*256 + ks*32 + hi*8;
    f32x4 a = *(const f32x4*)sp;
    f32x4 c = *(const f32x4*)(sp + 4);
    bf16x8 v;
    v[0]=(__bf16)a[0]; v[1]=(__bf16)a[1]; v[2]=(__bf16)a[2]; v[3]=(__bf16)a[3];
    v[4]=(__bf16)c[0]; v[5]=(__bf16)c[1]; v[6]=(__bf16)c[2]; v[7]=(__bf16)c[3];
    *(bf16x8*)(dst + (size_t)u*8) = v;
  }
}

// ---------------- K1c: repack feat32 -> featPK (B-operand for K2, k dim = node) ----
__global__ __launch_bounds__(256) void k1c_pack(
    const float* __restrict__ feat32, __bf16* __restrict__ featPK)
{
  int u = blockIdx.x*256 + threadIdx.x;    // 0..131071 (ks 0..127)
  int lane = u & 63, cf = (u>>6)&15, ks = u>>10;
  int lo = lane & 15, hi = lane >> 4;
  const float* sp = feat32 + (size_t)(ks*32 + hi*8)*256 + cf*16 + lo;
  bf16x8 v;
#pragma unroll
  for (int i = 0; i < 8; ++i) v[i] = (__bf16)sp[(size_t)i*256];
  *(bf16x8*)(featPK + (size_t)u*8) = v;
}

// ---------------- bucket sort rows by nmm ----------------
__global__ __launch_bounds__(1024) void kbucket(
    const int* __restrict__ nmm, int* __restrict__ perm,
    int* __restrict__ counts, int* __restrict__ baseo)
{
  __shared__ int cl[4], bl[4], cur[4];
  int t = threadIdx.x;
  if (t < 4) cl[t] = 0;
  __syncthreads();
  for (int i = t; i < NN; i += 1024) atomicAdd(&cl[nmm[i]], 1);
  __syncthreads();
  if (t == 0){ int b = 0; for (int s = 0; s < 4; ++s){ bl[s] = b; b += cl[s]; } }
  __syncthreads();
  if (t < 4){ counts[t] = cl[t]; baseo[t] = bl[t]; cur[t] = bl[t]; }
  __syncthreads();
  for (int i = t; i < NN; i += 1024){
    int s = nmm[i];
    int p = atomicAdd(&cur[s], 1);
    perm[p] = i;
  }
}

// ---------------- generic 64xK256x256 MFMA kernel --------------
// MODE 0: feat' = feature @ theta^T + b      (rows = n directly)
// MODE 1: node_projd (A=featB gathered by bucket s=combo, B=nodePack[s])
// MODE 2: inp_proj diff vs R -> recon_err    (A=featB gathered, B=reconPack[s*4+j])
// MODE 3: edge_projd (A=efB gathered rows (g,j), B=edgePack[s*4+j])
template<int MODE>
__global__ __launch_bounds__(256) void gk(
    const __bf16* __restrict__ packs,
    const float*  __restrict__ featureA,
    const __bf16* __restrict__ featBA,
    const __bf16* __restrict__ efBA,
    const float*  __restrict__ tb,
    const float*  __restrict__ Rb,
    float* __restrict__ feat32o, __bf16* __restrict__ featBo,
    float* __restrict__ nprojo,  float* __restrict__ eprojo,
    float* __restrict__ scal,
    const int* __restrict__ perm, const int* __restrict__ counts,
    const int* __restrict__ baseo)
{
  __shared__ __align__(16) __bf16 Al[64*264];   // row stride 264 (pad) -> 2-way banks
  __shared__ int gidx[64];
  __shared__ float rowsq[64];
  const int t = threadIdx.x, lane = t & 63, wv = t >> 6;
  const int tile = blockIdx.x, combo = blockIdx.y;
  int s = 0, j = 0, cnt;
  const __bf16* B;
  const int rbase = tile * 64;
  if constexpr (MODE == 0){
    cnt = NN; B = packs;
  } else {
    if constexpr (MODE == 1){ s = combo; } else { s = combo >> 2; j = combo & 3; }
    cnt = counts[s];
    if (rbase >= cnt) return;
    int matb;
    if constexpr (MODE == 1)      matb = 17 + combo;
    else if constexpr (MODE == 2) matb = 1  + combo;
    else                          matb = 21 + combo;
    B = packs + (size_t)matb * 65536;
  }
  // ---- stage A (64 rows x 256 k, bf16) ----
  {
    int r = t >> 2, seg = t & 3;
    int g;
    if constexpr (MODE == 0) g = rbase + r;
    else { int pos = rbase + r; g = (pos < cnt) ? perm[baseo[s] + pos] : -1; }
    if (seg == 0) gidx[r] = g;
    if (t < 64) rowsq[t] = 0.f;
    __bf16* dstrow = &Al[r*264 + seg*64];
    if constexpr (MODE == 0){
      const float* srcp = featureA + (size_t)g*256 + seg*64;
#pragma unroll
      for (int q = 0; q < 8; ++q){
        f32x4 a = *(const f32x4*)(srcp + q*8);
        f32x4 c = *(const f32x4*)(srcp + q*8 + 4);
        bf16x8 v;
        v[0]=(__bf16)a[0]; v[1]=(__bf16)a[1]; v[2]=(__bf16)a[2]; v[3]=(__bf16)a[3];
        v[4]=(__bf16)c[0]; v[5]=(__bf16)c[1]; v[6]=(__bf16)c[2]; v[7]=(__bf16)c[3];
        *(bf16x8*)(dstrow + q*8) = v;
      }
    } else {
      const __bf16* srcp;
      if constexpr (MODE == 3) srcp = efBA + ((size_t)g*4 + j)*256 + seg*64;
      else                     srcp = featBA + (size_t)g*256 + seg*64;
      bf16x8 z;
#pragma unroll
      for (int i = 0; i < 8; ++i) z[i] = (__bf16)0.f;
#pragma unroll
      for (int q = 0; q < 8; ++q){
        bf16x8 v = (g >= 0) ? *(const bf16x8*)(srcp + q*8) : z;
        *(bf16x8*)(dstrow + q*8) = v;
      }
    }
  }
  __syncthreads();
  // ---- MFMA: 4 rowfrags x (4 colfrags per wave) x 8 ksteps ----
  f32x4 acc[4][4];
#pragma unroll
  for (int a1 = 0; a1 < 4; ++a1)
#pragma unroll
    for (int a2 = 0; a2 < 4; ++a2){ f32x4 z = {0.f,0.f,0.f,0.f}; acc[a1][a2] = z; }
  const int m = lane & 15, h = lane >> 4;
#pragma unroll
  for (int ks = 0; ks < 8; ++ks){
    bf16x8 a[4];
#pragma unroll
    for (int rf = 0; rf < 4; ++rf)
      a[rf] = *(const bf16x8*)&Al[(rf*16 + m)*264 + ks*32 + h*8];
#pragma unroll
    for (int c4 = 0; c4 < 4; ++c4){
      int cf = wv*4 + c4;
      bf16x8 b = *(const bf16x8*)(B + ((size_t)(ks*16 + cf)*64 + lane)*8);
#pragma unroll
      for (int rf = 0; rf < 4; ++rf) acc[rf][c4] = mm_bf16(a[rf], b, acc[rf][c4]);
    }
  }
  // ---- epilogue ----
  if constexpr (MODE == 2){
#pragma unroll
    for (int rf = 0; rf < 4; ++rf)
#pragma unroll
      for (int reg = 0; reg < 4; ++reg){
        int row_l = rf*16 + h*4 + reg;
        int g2 = gidx[row_l];
        float sum = 0.f;
        if (g2 >= 0){
#pragma unroll
          for (int c4 = 0; c4 < 4; ++c4){
            int f = (wv*4 + c4)*16 + m;
            float d = acc[rf][c4][reg] - Rb[((size_t)g2*4 + j)*256 + f];
            sum += d*d;
          }
        }
        sum += __shfl_xor(sum, 1); sum += __shfl_xor(sum, 2);
        sum += __shfl_xor(sum, 4); sum += __shfl_xor(sum, 8);
        if (m == 0) atomicAdd(&rowsq[row_l], sum);
      }
    __syncthreads();
    if (t < 64){
      float e = sqrtf(rowsq[t]);
      e += __shfl_xor(e, 1);  e += __shfl_xor(e, 2);  e += __shfl_xor(e, 4);
      e += __shfl_xor(e, 8);  e += __shfl_xor(e, 16); e += __shfl_xor(e, 32);
      if (t == 0) atomicAdd(&scal[2], e);
    }
  } else {
#pragma unroll
    for (int rf = 0; rf < 4; ++rf)
#pragma unroll
      for (int c4 = 0; c4 < 4; ++c4){
        int f = (wv*4 + c4)*16 + m;
#pragma unroll
        for (int reg = 0; reg < 4; ++reg){
          int row_l = rf*16 + h*4 + reg;
          float val = acc[rf][c4][reg];
          if constexpr (MODE == 0){
            int n = rbase + row_l;
            float v2 = val + tb[f];
            feat32o[(size_t)n*256 + f] = v2;
            featBo[(size_t)n*256 + f] = (__bf16)v2;
          } else {
            int g2 = gidx[row_l];
            if (g2 >= 0){
              if constexpr (MODE == 1) nprojo[(size_t)g2*256 + f] = val;
              else eprojo[((size_t)g2*4 + j)*256 + f] = val;
            }
          }
        }
      }
  }
}

// ---------------- K2: ls = relu(linear*mask); R = ls @ feat'; l1,l2,edge_fea ----
__global__ __launch_bounds__(512) void k2_main(
    const float* __restrict__ linear, const float* __restrict__ maskp,
    const __bf16* __restrict__ featPK, const float* __restrict__ feat32,
    float* __restrict__ Rb, float* __restrict__ ef32, __bf16* __restrict__ efB,
    float* __restrict__ scal)
{
  __shared__ __align__(16) __bf16 Al[64*72];   // 64 rows x 64 k, stride 72 (pad)
  __shared__ float ninv[64];
  const int t = threadIdx.x, lane = t & 63, wv = t >> 6;
  const int R0 = blockIdx.x * 64;
  const int r = t >> 3, ko = (t & 7) * 8;
  const float* lp = linear + (size_t)(R0 + r)*4096 + ko;
  const float* mp = maskp  + (size_t)(R0 + r)*4096 + ko;
  f32x4 l0 = *(const f32x4*)lp, l1r = *(const f32x4*)(lp + 4);
  f32x4 m0 = *(const f32x4*)mp, m1r = *(const f32x4*)(mp + 4);
  float rs = 0.f, rq = 0.f;
  f32x4 acc[4][2];
#pragma unroll
  for (int a1 = 0; a1 < 4; ++a1)
#pragma unroll
    for (int a2 = 0; a2 < 2; ++a2){ f32x4 z = {0.f,0.f,0.f,0.f}; acc[a1][a2] = z; }
  const int m = lane & 15, h = lane >> 4;

  for (int kc = 0; kc < 64; ++kc){
    __syncthreads();                    // prev MFMA done before overwrite
    float v[8];
    v[0]=l0[0]*m0[0]; v[1]=l0[1]*m0[1]; v[2]=l0[2]*m0[2]; v[3]=l0[3]*m0[3];
    v[4]=l1r[0]*m1r[0]; v[5]=l1r[1]*m1r[1]; v[6]=l1r[2]*m1r[2]; v[7]=l1r[3]*m1r[3];
    bf16x8 pk;
#pragma unroll
    for (int i = 0; i < 8; ++i){
      float x = v[i] > 0.f ? v[i] : 0.f;
      rs += x; rq += x*x;
      pk[i] = (__bf16)x;
    }
    *(bf16x8*)&Al[r*72 + ko] = pk;
    if (kc < 63){                       // prefetch next chunk (in flight over MFMA)
      lp += 64; mp += 64;
      l0 = *(const f32x4*)lp; l1r = *(const f32x4*)(lp + 4);
      m0 = *(const f32x4*)mp; m1r = *(const f32x4*)(mp + 4);
    }
    __syncthreads();
#pragma unroll
    for (int kl = 0; kl < 2; ++kl){
      bf16x8 a[4];
#pragma unroll
      for (int rf = 0; rf < 4; ++rf)
        a[rf] = *(const bf16x8*)&Al[(rf*16 + m)*72 + kl*32 + h*8];
#pragma unroll
      for (int ci = 0; ci < 2; ++ci){
        int cf = wv*2 + ci;
        bf16x8 b = *(const bf16x8*)(featPK + ((size_t)((kc*2 + kl)*16 + cf)*64 + lane)*8);
#pragma unroll
        for (int rf = 0; rf < 4; ++rf) acc[rf][ci] = mm_bf16(a[rf], b, acc[rf][ci]);
      }
    }
  }
  // per-row reductions (8 lanes per row, same wave)
  rs += __shfl_xor(rs, 1); rs += __shfl_xor(rs, 2); rs += __shfl_xor(rs, 4);
  rq += __shfl_xor(rq, 1); rq += __shfl_xor(rq, 2); rq += __shfl_xor(rq, 4);
  if ((t & 7) == 0) ninv[r] = 1.f/(rs + 1.f);
  float c1 = ((t & 7) == 0) ? rs : 0.f;
  float c2 = ((t & 7) == 0) ? sqrtf(rq) : 0.f;
#pragma unroll
  for (int msk = 1; msk < 64; msk <<= 1){
    c1 += __shfl_xor(c1, msk); c2 += __shfl_xor(c2, msk);
  }
  if (lane == 0){ atomicAdd(&scal[0], c1); atomicAdd(&scal[1], c2); }
  __syncthreads();
  // stores: R, edge_fea = (R + feat')*ninv
#pragma unroll
  for (int rf = 0; rf < 4; ++rf)
#pragma unroll
    for (int ci = 0; ci < 2; ++ci){
      int f = (wv*2 + ci)*16 + m;
#pragma unroll
      for (int reg = 0; reg < 4; ++reg){
        int row_l = rf*16 + h*4 + reg;
        float val = acc[rf][ci][reg];
        size_t gi = (size_t)(R0 + row_l)*256 + f;
        Rb[gi] = val;
        int n = (R0 + row_l) >> 2;
        float e = (val + feat32[(size_t)n*256 + f]) * ninv[row_l];
        ef32[gi] = e;
        efB[gi] = (__bf16)e;
      }
    }
}

// ---------------- K6: head-softmax attention + node_rep ----------------
__global__ __launch_bounds__(256) void k6_attn(
    const float* __restrict__ nproj, const float* __restrict__ eproj,
    const float* __restrict__ ef32, float* __restrict__ nrep)
{
  const int i = blockIdx.x, f = threadIdx.x, hh = f >> 5;
  __shared__ float sc[4][8];
  float np = nproj[(size_t)i*256 + f] * 0.17677669529663689f;  // 1/sqrt(32)
#pragma unroll
  for (int t4 = 0; t4 < 4; ++t4){
    float p = np * eproj[((size_t)i*4 + t4)*256 + f];
    p += __shfl_xor(p, 16); p += __shfl_xor(p, 8); p += __shfl_xor(p, 4);
    p += __shfl_xor(p, 2);  p += __shfl_xor(p, 1);
    if ((f & 31) == 0) sc[t4][hh] = p;
  }
  __syncthreads();
  float accv = 0.f;
#pragma unroll
  for (int t4 = 0; t4 < 4; ++t4){
    float mx = sc[t4][0];
#pragma unroll
    for (int q = 1; q < 8; ++q) mx = fmaxf(mx, sc[t4][q]);
    float den = 0.f;
#pragma unroll
    for (int q = 0; q < 8; ++q) den += expf(sc[t4][q] - mx);
    float w = expf(sc[t4][hh] - mx) / den;
    float x = w * ef32[((size_t)i*4 + t4)*256 + f];
    accv += x > 0.f ? x : 0.f;
  }
  nrep[(size_t)i*256 + f] = accv;
}

// ---------------- loss finalize ----------------
__global__ void k_loss(const float* __restrict__ scal, float* __restrict__ o){
  if (threadIdx.x == 0 && blockIdx.x == 0)
    o[0] = 0.1f*(0.01f*scal[2] + 0.2f*scal[1] + scal[0]);
}

// ---------------- K7: predict = softmax(sigmoid(nr[idx]@pw^T + pb)) ----------------
__global__ __launch_bounds__(256) void k7_pred(
    const float* __restrict__ nrep, const int* __restrict__ nidx,
    const float* __restrict__ pw, const float* __restrict__ pb,
    float* __restrict__ outp)
{
  __shared__ float pwT[256*16];
  const int t = threadIdx.x;
  {
    int c0 = t & 15, k0 = (t >> 4) * 16;
    for (int kk = 0; kk < 16; ++kk)
      pwT[(k0 + kk)*16 + c0] = pw[(size_t)c0*256 + k0 + kk];
  }
  __syncthreads();
  const int c = t & 15, r0 = t >> 4;
  float pbv = pb[c];
  for (int rr = 0; rr < 4; ++rr){
    int p = blockIdx.x*64 + rr*16 + r0;
    int i = nidx[p];
    const float* nr = nrep + (size_t)i*256;
    float acc = pbv;
    for (int k = 0; k < 256; ++k) acc += nr[k]*pwT[k*16 + c];
    float sg = 1.f/(1.f + expf(-acc));
    float mx = sg;
    mx = fmaxf(mx, __shfl_xor(mx, 1)); mx = fmaxf(mx, __shfl_xor(mx, 2));
    mx = fmaxf(mx, __shfl_xor(mx, 4)); mx = fmaxf(mx, __shfl_xor(mx, 8));
    float ex = expf(sg - mx);
    float den = ex;
    den += __shfl_xor(den, 1); den += __shfl_xor(den, 2);
    den += __shfl_xor(den, 4); den += __shfl_xor(den, 8);
    outp[(size_t)p*16 + c] = ex/den;
  }
}

extern "C" void kernel_launch(void* const* d_in, const int* in_sizes, int n_in,
                              void* d_out, int out_size, void* d_ws, size_t ws_size,
                              hipStream_t stream)
{
  (void)in_sizes; (void)n_in; (void)out_size; (void)ws_size;
  const float* feature = (const float*)d_in[0];
  const float* maskp   = (const float*)d_in[1];
  const int*   nmm     = (const int*)d_in[2];
  const int*   nidx    = (const int*)d_in[3];
  const float* theta_w = (const float*)d_in[4];
  const float* theta_b = (const float*)d_in[5];
  const float* linear  = (const float*)d_in[6];
  const float* recon_p = (const float*)d_in[7];
  const float* node_p  = (const float*)d_in[8];
  const float* edge_p  = (const float*)d_in[9];
  const float* pred_w  = (const float*)d_in[10];
  const float* pred_b  = (const float*)d_in[11];
  float* out = (float*)d_out;
  char* ws = (char*)d_ws;

  float* scal   = (float*)(ws + OFF_SCAL);
  int*   counts = (int*)(ws + OFF_CNT);
  int*   baseo  = (int*)(ws + OFF_BASE);
  int*   perm   = (int*)(ws + OFF_PERM);
  float* feat32 = (float*)(ws + OFF_FEAT32);
  __bf16* featB  = (__bf16*)(ws + OFF_FEATB);
  __bf16* featPK = (__bf16*)(ws + OFF_FEATPK);
  __bf16* packs  = (__bf16*)(ws + OFF_PACKS);
  float* Rbuf   = (float*)(ws + OFF_R);
  float* ef32   = (float*)(ws + OFF_EF32);
  __bf16* efB    = (__bf16*)(ws + OFF_EFB);
  float* nproj  = (float*)(ws + OFF_NPROJ);
  float* eproj  = (float*)(ws + OFF_EPROJ);

  float* out_pred = out;            // [1024,16]
  float* out_loss = out + 16384;    // scalar
  float* out_nrep = out + 16385;    // [4096,256]

  hipMemsetAsync(d_ws, 0, 96, stream);

  k1b_pack<<<37, 256, 0, stream>>>(theta_w, recon_p, node_p, edge_p, packs);

  gk<0><<<dim3(64, 1), 256, 0, stream>>>(packs, feature, nullptr, nullptr, theta_b,
      nullptr, feat32, featB, nullptr, nullptr, scal, perm, counts, baseo);

  k1c_pack<<<512, 256, 0, stream>>>(feat32, featPK);

  kbucket<<<1, 1024, 0, stream>>>(nmm, perm, counts, baseo);

  k2_main<<<256, 512, 0, stream>>>(linear, maskp, featPK, feat32,
                                   Rbuf, ef32, efB, scal);

  gk<2><<<dim3(64, 16), 256, 0, stream>>>(packs, nullptr, featB, nullptr, nullptr,
      Rbuf, nullptr, nullptr, nullptr, nullptr, scal, perm, counts, baseo);

  gk<3><<<dim3(64, 16), 256, 0, stream>>>(packs, nullptr, featB, efB, nullptr,
      nullptr, nullptr, nullptr, nullptr, eproj, scal, perm, counts, baseo);

  gk<1><<<dim3(64, 4), 256, 0, stream>>>(packs, nullptr, featB, nullptr, nullptr,
      nullptr, nullptr, nullptr, nproj, nullptr, scal, perm, counts, baseo);

  k6_attn<<<4096, 256, 0, stream>>>(nproj, eproj, ef32, out_nrep);

  k_loss<<<1, 64, 0, stream>>>(scal, out_loss);

  k7_pred<<<16, 256, 0, stream>>>(out_nrep, nidx, pred_w, pred_b, out_pred);
}

// Round 2
// 725.741 us; speedup vs baseline: 1.1673x; 1.1673x over previous
//
#include <hip/hip_runtime.h>
#include <hip/hip_bf16.h>
#include <math.h>

// Sizes: N=4096, T=4, F=256, H=8, C=16, P=1024, D=32
#define NN 4096
#define NTROWS 16384   // N*T

typedef __attribute__((ext_vector_type(8))) __bf16 bf16x8;
typedef __attribute__((ext_vector_type(4))) float f32x4;

// ---------------- workspace layout (bytes) ----------------
static constexpr size_t OFF_SCAL   = 0;          // float[16]: 0=l1 1=l2 2=recon_err
static constexpr size_t OFF_CNT    = 64;         // int[4]
static constexpr size_t OFF_BASE   = 80;         // int[4]
static constexpr size_t OFF_PERM   = 256;        // int[4096]
static constexpr size_t OFF_FEAT32 = 16896;      // N*F f32      (4 MB)
static constexpr size_t OFF_FEATB  = 4211200;    // N*F bf16     (2 MB)
static constexpr size_t OFF_FEATPK = 6308352;    // N*F bf16 packed (2 MB)
static constexpr size_t OFF_PACKS  = 8405504;    // 37 * 65536 bf16 (4.85 MB)
static constexpr size_t OFF_R      = 13255168;   // NT*F f32     (16 MB)
static constexpr size_t OFF_RSUM   = 30032384;   // NT f32       (64 KB)
static constexpr size_t OFF_RSQ    = 30097920;   // NT f32       (64 KB)
static constexpr size_t OFF_EF32   = 30163456;   // NT*F f32     (16 MB)
static constexpr size_t OFF_EFB    = 46940672;   // NT*F bf16    (8 MB)
static constexpr size_t OFF_NPROJ  = 55329280;   // N*F f32      (4 MB)
static constexpr size_t OFF_EPROJ  = 59523584;   // NT*F f32     (16 MB) end 76300800

__device__ __forceinline__ f32x4 mm_bf16(bf16x8 a, bf16x8 b, f32x4 c){
  return __builtin_amdgcn_mfma_f32_16x16x32_bf16(a, b, c, 0, 0, 0);
}

// ---------------- K1b: pack all B matrices (theta + 16 recon + 4 node + 16 edge) ----
// Pack layout per matrix (65536 bf16): unit u=(ks*16+cf)*64+lane, element i:
//   packed[u*8+i] = mat[cf*16 + (lane&15)][ks*32 + (lane>>4)*8 + i]
__global__ __launch_bounds__(256) void k1b_pack(
    const float* __restrict__ theta, const float* __restrict__ recp,
    const float* __restrict__ nodp,  const float* __restrict__ edgp,
    __bf16* __restrict__ packs)
{
  int b = blockIdx.x;
  const float* src;
  if (b == 0)       src = theta;
  else if (b < 17)  src = recp + (size_t)(b-1)*65536;
  else if (b < 21)  src = nodp + (size_t)(b-17)*65536;
  else              src = edgp + (size_t)(b-21)*65536;
  __bf16* dst = packs + (size_t)b*65536;
  for (int it = 0; it < 32; ++it){
    int u = it*256 + threadIdx.x;
    int lane = u & 63, cf = (u>>6)&15, ks = u>>10;
    int lo = lane & 15, hi = lane >> 4;
    const float* sp = src + (size_t)(cf*16+lo)*256 + ks*32 + hi*8;
    f32x4 a = *(const f32x4*)sp;
    f32x4 c = *(const f32x4*)(sp + 4);
    bf16x8 v;
    v[0]=(__bf16)a[0]; v[1]=(__bf16)a[1]; v[2]=(__bf16)a[2]; v[3]=(__bf16)a[3];
    v[4]=(__bf16)c[0]; v[5]=(__bf16)c[1]; v[6]=(__bf16)c[2]; v[7]=(__bf16)c[3];
    *(bf16x8*)(dst + (size_t)u*8) = v;
  }
}

// ---------------- K1c: repack feat32 -> featPK (B-operand for K2, k dim = node) ----
__global__ __launch_bounds__(256) void k1c_pack(
    const float* __restrict__ feat32, __bf16* __restrict__ featPK)
{
  int u = blockIdx.x*256 + threadIdx.x;    // 0..131071 (ks 0..127)
  int lane = u & 63, cf = (u>>6)&15, ks = u>>10;
  int lo = lane & 15, hi = lane >> 4;
  const float* sp = feat32 + (size_t)(ks*32 + hi*8)*256 + cf*16 + lo;
  bf16x8 v;
#pragma unroll
  for (int i = 0; i < 8; ++i) v[i] = (__bf16)sp[(size_t)i*256];
  *(bf16x8*)(featPK + (size_t)u*8) = v;
}

// ---------------- bucket sort rows by nmm (ballot-based, no hot atomics) ----------
__global__ __launch_bounds__(1024) void kbucket(
    const int* __restrict__ nmm, int* __restrict__ perm,
    int* __restrict__ counts, int* __restrict__ baseo)
{
  __shared__ int segoff[64][4];   // per (iter*16+wave) per bucket: count then prefix
  __shared__ int bl[4];
  const int t = threadIdx.x, lane = t & 63, w = t >> 6;
  int sv[4];
#pragma unroll
  for (int it = 0; it < 4; ++it){
    int i = it*1024 + t;
    int s = nmm[i];
    sv[it] = s;
#pragma unroll
    for (int b = 0; b < 4; ++b){
      unsigned long long mb = __ballot(s == b);
      if (lane == 0) segoff[it*16 + w][b] = __popcll(mb);
    }
  }
  __syncthreads();
  if (t < 4){            // serial prefix over 64 segments for bucket t
    int b = t, run = 0;
    for (int seg = 0; seg < 64; ++seg){
      int c = segoff[seg][b]; segoff[seg][b] = run; run += c;
    }
    counts[b] = run;
  }
  __syncthreads();
  if (t == 0){
    int b0 = 0;
    for (int s = 0; s < 4; ++s){ bl[s] = b0; baseo[s] = b0; b0 += counts[s]; }
  }
  __syncthreads();
#pragma unroll
  for (int it = 0; it < 4; ++it){
    int i = it*1024 + t;
    int s = sv[it];
    int rank = 0;
#pragma unroll
    for (int b = 0; b < 4; ++b){
      unsigned long long mb = __ballot(s == b);
      if (s == b) rank = __popcll(mb & ((1ull << lane) - 1ull));
    }
    perm[bl[s] + segoff[it*16 + w][s] + rank] = i;
  }
}

// ---------------- K0: feat' = feature @ theta^T + b  (64-row tiles) --------------
__global__ __launch_bounds__(256) void k0_feat(
    const __bf16* __restrict__ packs, const float* __restrict__ featureA,
    const float* __restrict__ tb,
    float* __restrict__ feat32o, __bf16* __restrict__ featBo)
{
  __shared__ __align__(16) __bf16 Al[64*264];
  const int t = threadIdx.x, lane = t & 63, wv = t >> 6;
  const int rbase = blockIdx.x * 64;
  const __bf16* B = packs;
  {
    int r = t >> 2, seg = t & 3;
    const float* srcp = featureA + (size_t)(rbase + r)*256 + seg*64;
    __bf16* dstrow = &Al[r*264 + seg*64];
#pragma unroll
    for (int q = 0; q < 8; ++q){
      f32x4 a = *(const f32x4*)(srcp + q*8);
      f32x4 c = *(const f32x4*)(srcp + q*8 + 4);
      bf16x8 v;
      v[0]=(__bf16)a[0]; v[1]=(__bf16)a[1]; v[2]=(__bf16)a[2]; v[3]=(__bf16)a[3];
      v[4]=(__bf16)c[0]; v[5]=(__bf16)c[1]; v[6]=(__bf16)c[2]; v[7]=(__bf16)c[3];
      *(bf16x8*)(dstrow + q*8) = v;
    }
  }
  __syncthreads();
  f32x4 acc[4][4];
#pragma unroll
  for (int a1 = 0; a1 < 4; ++a1)
#pragma unroll
    for (int a2 = 0; a2 < 4; ++a2){ f32x4 z = {0.f,0.f,0.f,0.f}; acc[a1][a2] = z; }
  const int m = lane & 15, h = lane >> 4;
#pragma unroll
  for (int ks = 0; ks < 8; ++ks){
    bf16x8 a[4];
#pragma unroll
    for (int rf = 0; rf < 4; ++rf)
      a[rf] = *(const bf16x8*)&Al[(rf*16 + m)*264 + ks*32 + h*8];
#pragma unroll
    for (int c4 = 0; c4 < 4; ++c4){
      int cf = wv*4 + c4;
      bf16x8 b = *(const bf16x8*)(B + ((size_t)(ks*16 + cf)*64 + lane)*8);
#pragma unroll
      for (int rf = 0; rf < 4; ++rf) acc[rf][c4] = mm_bf16(a[rf], b, acc[rf][c4]);
    }
  }
#pragma unroll
  for (int rf = 0; rf < 4; ++rf)
#pragma unroll
    for (int c4 = 0; c4 < 4; ++c4){
      int f = (wv*4 + c4)*16 + m;
#pragma unroll
      for (int reg = 0; reg < 4; ++reg){
        int n = rbase + rf*16 + h*4 + reg;
        float v2 = acc[rf][c4][reg] + tb[f];
        feat32o[(size_t)n*256 + f] = v2;
        featBo[(size_t)n*256 + f] = (__bf16)v2;
      }
    }
}

// ---------------- K2: ls = relu(linear*mask); partial R += ls_slice @ feat' ------
// grid (256 row-tiles, 4 K-splits); 4 blocks/CU for TLP. b-loads issued FIRST each
// chunk so the compiler emits counted vmcnt waits (A-prefetch stays in flight).
__global__ __launch_bounds__(512, 4) void k2_main(
    const float* __restrict__ linear, const float* __restrict__ maskp,
    const __bf16* __restrict__ featPK,
    float* __restrict__ Rb, float* __restrict__ rowsum, float* __restrict__ rowsq)
{
  __shared__ __align__(16) __bf16 Al[2][64*72];
  const int t = threadIdx.x, lane = t & 63, wv = t >> 6;
  const int R0 = blockIdx.x * 64;
  const int ksl = blockIdx.y;              // K-split 0..3, 1024 k each
  const int r = t >> 3, ko = (t & 7) * 8;
  const float* lp = linear + (size_t)(R0 + r)*4096 + ksl*1024 + ko;
  const float* mp = maskp  + (size_t)(R0 + r)*4096 + ksl*1024 + ko;
  const __bf16* Bp = featPK + (((size_t)(ksl*32)*16 + wv*2)*64 + lane)*8;
  f32x4 l0 = *(const f32x4*)lp, l1r = *(const f32x4*)(lp + 4);
  f32x4 m0 = *(const f32x4*)mp, m1r = *(const f32x4*)(mp + 4);
  float rs = 0.f, rq = 0.f;
  f32x4 acc[4][2];
#pragma unroll
  for (int a1 = 0; a1 < 4; ++a1)
#pragma unroll
    for (int a2 = 0; a2 < 2; ++a2){ f32x4 z = {0.f,0.f,0.f,0.f}; acc[a1][a2] = z; }
  const int m = lane & 15, h = lane >> 4;

  for (int kc = 0; kc < 16; ++kc){
    // 1) issue B loads for this chunk FIRST (oldest-but-b outstanding = A(kc))
    bf16x8 b[2][2];
#pragma unroll
    for (int kl = 0; kl < 2; ++kl)
#pragma unroll
      for (int ci = 0; ci < 2; ++ci)
        b[kl][ci] = *(const bf16x8*)(Bp + (size_t)(kc*2 + kl)*8192 + ci*512);
    __builtin_amdgcn_sched_barrier(0);
    // 2) elementwise (waits A(kc) with counted vmcnt; b still in flight)
    float v[8];
    v[0]=l0[0]*m0[0]; v[1]=l0[1]*m0[1]; v[2]=l0[2]*m0[2]; v[3]=l0[3]*m0[3];
    v[4]=l1r[0]*m1r[0]; v[5]=l1r[1]*m1r[1]; v[6]=l1r[2]*m1r[2]; v[7]=l1r[3]*m1r[3];
    bf16x8 pk;
#pragma unroll
    for (int i = 0; i < 8; ++i){
      float x = v[i] > 0.f ? v[i] : 0.f;
      rs += x; rq += x*x;
      pk[i] = (__bf16)x;
    }
    *(bf16x8*)&Al[kc & 1][r*72 + ko] = pk;
    // 3) prefetch A for next chunk (left in flight across the MFMA phase)
    if (kc < 15){
      lp += 64; mp += 64;
      l0 = *(const f32x4*)lp; l1r = *(const f32x4*)(lp + 4);
      m0 = *(const f32x4*)mp; m1r = *(const f32x4*)(mp + 4);
    }
    __builtin_amdgcn_sched_barrier(0);
    __syncthreads();
    // 4) MFMA (waits b with counted vmcnt; A(kc+1) stays outstanding)
#pragma unroll
    for (int kl = 0; kl < 2; ++kl){
      bf16x8 a[4];
#pragma unroll
      for (int rf = 0; rf < 4; ++rf)
        a[rf] = *(const bf16x8*)&Al[kc & 1][(rf*16 + m)*72 + kl*32 + h*8];
#pragma unroll
      for (int ci = 0; ci < 2; ++ci)
#pragma unroll
        for (int rf = 0; rf < 4; ++rf) acc[rf][ci] = mm_bf16(a[rf], b[kl][ci], acc[rf][ci]);
    }
  }
  // per-row partial sums (8 lanes per row, same wave)
  rs += __shfl_xor(rs, 1); rs += __shfl_xor(rs, 2); rs += __shfl_xor(rs, 4);
  rq += __shfl_xor(rq, 1); rq += __shfl_xor(rq, 2); rq += __shfl_xor(rq, 4);
  if ((t & 7) == 0){
    atomicAdd(&rowsum[R0 + r], rs);
    atomicAdd(&rowsq[R0 + r], rq);
  }
  // partial R accumulate
#pragma unroll
  for (int rf = 0; rf < 4; ++rf)
#pragma unroll
    for (int ci = 0; ci < 2; ++ci){
      int f = (wv*2 + ci)*16 + m;
#pragma unroll
      for (int reg = 0; reg < 4; ++reg){
        int row_l = rf*16 + h*4 + reg;
        atomicAdd(&Rb[(size_t)(R0 + row_l)*256 + f], acc[rf][ci][reg]);
      }
    }
}

// ---------------- K2b: edge_fea + l1/l2 finalize --------------------------------
__global__ __launch_bounds__(256) void k2b(
    const float* __restrict__ Rb, const float* __restrict__ feat32,
    const float* __restrict__ rowsum, const float* __restrict__ rowsq,
    float* __restrict__ ef32, __bf16* __restrict__ efB, float* __restrict__ scal)
{
  const int t = threadIdx.x;
  const int row0 = blockIdx.x * 16;
#pragma unroll 4
  for (int rr = 0; rr < 16; ++rr){
    int row = row0 + rr, n = row >> 2;
    float ninv = 1.f / (rowsum[row] + 1.f);
    size_t gi = (size_t)row*256 + t;
    float e = (Rb[gi] + feat32[(size_t)n*256 + t]) * ninv;
    ef32[gi] = e;
    efB[gi] = (__bf16)e;
  }
  float c1 = 0.f, c2 = 0.f;
  if (t < 16){ int row = row0 + t; c1 = rowsum[row]; c2 = sqrtf(rowsq[row]); }
  c1 += __shfl_xor(c1, 1); c1 += __shfl_xor(c1, 2); c1 += __shfl_xor(c1, 4); c1 += __shfl_xor(c1, 8);
  c2 += __shfl_xor(c2, 1); c2 += __shfl_xor(c2, 2); c2 += __shfl_xor(c2, 4); c2 += __shfl_xor(c2, 8);
  if (t == 0){ atomicAdd(&scal[0], c1); atomicAdd(&scal[1], c2); }
}

// ---------------- gk_all: modes 1/2/3 merged (36 combos in blockIdx.y) ----------
// y 0..15:  recon diff -> recon_err   (s=y>>2, j=y&3,  B=packs[1+y],  A=featB)
// y 16..31: edge_projd               (s,j as above,    B=packs[21+y2], A=efB)
// y 32..35: node_projd               (s=y-32,          B=packs[17+s],  A=featB)
__global__ __launch_bounds__(256) void gk_all(
    const __bf16* __restrict__ packs, const __bf16* __restrict__ featB,
    const __bf16* __restrict__ efB, const float* __restrict__ Rb,
    float* __restrict__ nproj, float* __restrict__ eproj, float* __restrict__ scal,
    const int* __restrict__ perm, const int* __restrict__ counts,
    const int* __restrict__ baseo)
{
  __shared__ __align__(16) __bf16 Al[64*264];
  __shared__ int gidx[64];
  __shared__ float rowsq_l[64];
  const int t = threadIdx.x, lane = t & 63, wv = t >> 6;
  const int y = blockIdx.y;
  int mode, s, j, matb;
  if (y < 16){ mode = 2; s = y >> 2; j = y & 3; matb = 1 + y; }
  else if (y < 32){ int y2 = y - 16; mode = 3; s = y2 >> 2; j = y2 & 3; matb = 21 + y2; }
  else { mode = 1; s = y - 32; j = 0; matb = 17 + s; }
  const int cnt = counts[s];
  const int rbase = blockIdx.x * 64;
  if (rbase >= cnt) return;
  const __bf16* B = packs + (size_t)matb * 65536;
  // ---- stage A ----
  {
    int r = t >> 2, seg = t & 3;
    int pos = rbase + r;
    int g = (pos < cnt) ? perm[baseo[s] + pos] : -1;
    if (seg == 0) gidx[r] = g;
    if (t < 64) rowsq_l[t] = 0.f;
    const __bf16* srcp = (mode == 3) ? efB + ((size_t)g*4 + j)*256 + seg*64
                                     : featB + (size_t)g*256 + seg*64;
    __bf16* dstrow = &Al[r*264 + seg*64];
    bf16x8 z;
#pragma unroll
    for (int i = 0; i < 8; ++i) z[i] = (__bf16)0.f;
#pragma unroll
    for (int q = 0; q < 8; ++q){
      bf16x8 v = (g >= 0) ? *(const bf16x8*)(srcp + q*8) : z;
      *(bf16x8*)(dstrow + q*8) = v;
    }
  }
  __syncthreads();
  f32x4 acc[4][4];
#pragma unroll
  for (int a1 = 0; a1 < 4; ++a1)
#pragma unroll
    for (int a2 = 0; a2 < 4; ++a2){ f32x4 z = {0.f,0.f,0.f,0.f}; acc[a1][a2] = z; }
  const int m = lane & 15, h = lane >> 4;
#pragma unroll
  for (int ks = 0; ks < 8; ++ks){
    bf16x8 a[4];
#pragma unroll
    for (int rf = 0; rf < 4; ++rf)
      a[rf] = *(const bf16x8*)&Al[(rf*16 + m)*264 + ks*32 + h*8];
#pragma unroll
    for (int c4 = 0; c4 < 4; ++c4){
      int cf = wv*4 + c4;
      bf16x8 b = *(const bf16x8*)(B + ((size_t)(ks*16 + cf)*64 + lane)*8);
#pragma unroll
      for (int rf = 0; rf < 4; ++rf) acc[rf][c4] = mm_bf16(a[rf], b, acc[rf][c4]);
    }
  }
  // ---- epilogue ----
  if (mode == 2){
#pragma unroll
    for (int rf = 0; rf < 4; ++rf)
#pragma unroll
      for (int reg = 0; reg < 4; ++reg){
        int row_l = rf*16 + h*4 + reg;
        int g2 = gidx[row_l];
        float sum = 0.f;
        if (g2 >= 0){
#pragma unroll
          for (int c4 = 0; c4 < 4; ++c4){
            int f = (wv*4 + c4)*16 + m;
            float d = acc[rf][c4][reg] - Rb[((size_t)g2*4 + j)*256 + f];
            sum += d*d;
          }
        }
        sum += __shfl_xor(sum, 1); sum += __shfl_xor(sum, 2);
        sum += __shfl_xor(sum, 4); sum += __shfl_xor(sum, 8);
        if (m == 0) atomicAdd(&rowsq_l[row_l], sum);
      }
    __syncthreads();
    if (t < 64){
      float e = sqrtf(rowsq_l[t]);
      e += __shfl_xor(e, 1);  e += __shfl_xor(e, 2);  e += __shfl_xor(e, 4);
      e += __shfl_xor(e, 8);  e += __shfl_xor(e, 16); e += __shfl_xor(e, 32);
      if (t == 0) atomicAdd(&scal[2], e);
    }
  } else {
#pragma unroll
    for (int rf = 0; rf < 4; ++rf)
#pragma unroll
      for (int c4 = 0; c4 < 4; ++c4){
        int f = (wv*4 + c4)*16 + m;
#pragma unroll
        for (int reg = 0; reg < 4; ++reg){
          int row_l = rf*16 + h*4 + reg;
          int g2 = gidx[row_l];
          if (g2 >= 0){
            if (mode == 1) nproj[(size_t)g2*256 + f] = acc[rf][c4][reg];
            else           eproj[((size_t)g2*4 + j)*256 + f] = acc[rf][c4][reg];
          }
        }
      }
  }
}

// ---------------- K6: head-softmax attention + node_rep ----------------
__global__ __launch_bounds__(256) void k6_attn(
    const float* __restrict__ nproj, const float* __restrict__ eproj,
    const float* __restrict__ ef32, float* __restrict__ nrep)
{
  const int i = blockIdx.x, f = threadIdx.x, hh = f >> 5;
  __shared__ float sc[4][8];
  float np = nproj[(size_t)i*256 + f] * 0.17677669529663689f;  // 1/sqrt(32)
#pragma unroll
  for (int t4 = 0; t4 < 4; ++t4){
    float p = np * eproj[((size_t)i*4 + t4)*256 + f];
    p += __shfl_xor(p, 16); p += __shfl_xor(p, 8); p += __shfl_xor(p, 4);
    p += __shfl_xor(p, 2);  p += __shfl_xor(p, 1);
    if ((f & 31) == 0) sc[t4][hh] = p;
  }
  __syncthreads();
  float accv = 0.f;
#pragma unroll
  for (int t4 = 0; t4 < 4; ++t4){
    float mx = sc[t4][0];
#pragma unroll
    for (int q = 1; q < 8; ++q) mx = fmaxf(mx, sc[t4][q]);
    float den = 0.f;
#pragma unroll
    for (int q = 0; q < 8; ++q) den += expf(sc[t4][q] - mx);
    float w = expf(sc[t4][hh] - mx) / den;
    float x = w * ef32[((size_t)i*4 + t4)*256 + f];
    accv += x > 0.f ? x : 0.f;
  }
  nrep[(size_t)i*256 + f] = accv;
}

// ---------------- loss finalize ----------------
__global__ void k_loss(const float* __restrict__ scal, float* __restrict__ o){
  if (threadIdx.x == 0 && blockIdx.x == 0)
    o[0] = 0.1f*(0.01f*scal[2] + 0.2f*scal[1] + scal[0]);
}

// ---------------- K7: predict = softmax(sigmoid(nr[idx]@pw^T + pb)) ----------------
__global__ __launch_bounds__(256) void k7_pred(
    const float* __restrict__ nrep, const int* __restrict__ nidx,
    const float* __restrict__ pw, const float* __restrict__ pb,
    float* __restrict__ outp)
{
  __shared__ float pwT[256*16];
  const int t = threadIdx.x;
  {
    int c0 = t & 15, k0 = (t >> 4) * 16;
    for (int kk = 0; kk < 16; ++kk)
      pwT[(k0 + kk)*16 + c0] = pw[(size_t)c0*256 + k0 + kk];
  }
  __syncthreads();
  const int c = t & 15, r0 = t >> 4;
  float pbv = pb[c];
  for (int rr = 0; rr < 4; ++rr){
    int p = blockIdx.x*64 + rr*16 + r0;
    int i = nidx[p];
    const float* nr = nrep + (size_t)i*256;
    float acc = pbv;
    for (int k = 0; k < 256; ++k) acc += nr[k]*pwT[k*16 + c];
    float sg = 1.f/(1.f + expf(-acc));
    float mx = sg;
    mx = fmaxf(mx, __shfl_xor(mx, 1)); mx = fmaxf(mx, __shfl_xor(mx, 2));
    mx = fmaxf(mx, __shfl_xor(mx, 4)); mx = fmaxf(mx, __shfl_xor(mx, 8));
    float ex = expf(sg - mx);
    float den = ex;
    den += __shfl_xor(den, 1); den += __shfl_xor(den, 2);
    den += __shfl_xor(den, 4); den += __shfl_xor(den, 8);
    outp[(size_t)p*16 + c] = ex/den;
  }
}

extern "C" void kernel_launch(void* const* d_in, const int* in_sizes, int n_in,
                              void* d_out, int out_size, void* d_ws, size_t ws_size,
                              hipStream_t stream)
{
  (void)in_sizes; (void)n_in; (void)out_size; (void)ws_size;
  const float* feature = (const float*)d_in[0];
  const float* maskp   = (const float*)d_in[1];
  const int*   nmm     = (const int*)d_in[2];
  const int*   nidx    = (const int*)d_in[3];
  const float* theta_w = (const float*)d_in[4];
  const float* theta_b = (const float*)d_in[5];
  const float* linear  = (const float*)d_in[6];
  const float* recon_p = (const float*)d_in[7];
  const float* node_p  = (const float*)d_in[8];
  const float* edge_p  = (const float*)d_in[9];
  const float* pred_w  = (const float*)d_in[10];
  const float* pred_b  = (const float*)d_in[11];
  float* out = (float*)d_out;
  char* ws = (char*)d_ws;

  float* scal   = (float*)(ws + OFF_SCAL);
  int*   counts = (int*)(ws + OFF_CNT);
  int*   baseo  = (int*)(ws + OFF_BASE);
  int*   perm   = (int*)(ws + OFF_PERM);
  float* feat32 = (float*)(ws + OFF_FEAT32);
  __bf16* featB  = (__bf16*)(ws + OFF_FEATB);
  __bf16* featPK = (__bf16*)(ws + OFF_FEATPK);
  __bf16* packs  = (__bf16*)(ws + OFF_PACKS);
  float* Rbuf   = (float*)(ws + OFF_R);
  float* rowsum = (float*)(ws + OFF_RSUM);
  float* rowsq  = (float*)(ws + OFF_RSQ);
  float* ef32   = (float*)(ws + OFF_EF32);
  __bf16* efB    = (__bf16*)(ws + OFF_EFB);
  float* nproj  = (float*)(ws + OFF_NPROJ);
  float* eproj  = (float*)(ws + OFF_EPROJ);

  float* out_pred = out;            // [1024,16]
  float* out_loss = out + 16384;    // scalar
  float* out_nrep = out + 16385;    // [4096,256]

  hipMemsetAsync(ws + OFF_SCAL, 0, 96, stream);
  hipMemsetAsync(ws + OFF_R, 0, 16777216 + 131072, stream);  // R + rowsum + rowsq

  kbucket<<<1, 1024, 0, stream>>>(nmm, perm, counts, baseo);

  k1b_pack<<<37, 256, 0, stream>>>(theta_w, recon_p, node_p, edge_p, packs);

  k0_feat<<<64, 256, 0, stream>>>(packs, feature, theta_b, feat32, featB);

  k1c_pack<<<512, 256, 0, stream>>>(feat32, featPK);

  k2_main<<<dim3(256, 4), 512, 0, stream>>>(linear, maskp, featPK,
                                            Rbuf, rowsum, rowsq);

  k2b<<<1024, 256, 0, stream>>>(Rbuf, feat32, rowsum, rowsq, ef32, efB, scal);

  gk_all<<<dim3(64, 36), 256, 0, stream>>>(packs, featB, efB, Rbuf,
      nproj, eproj, scal, perm, counts, baseo);

  k6_attn<<<4096, 256, 0, stream>>>(nproj, eproj, ef32, out_nrep);

  k_loss<<<1, 64, 0, stream>>>(scal, out_loss);

  k7_pred<<<16, 256, 0, stream>>>(out_nrep, nidx, pred_w, pred_b, out_pred);
}